// Round 12
// baseline (109.413 us; speedup 1.0000x reference)
//
#include <hip/hip_runtime.h>

// Deformable conv (K=3, stride=1, pad=1, dil=1), N=8, Cin=Cout=128, H=W=64.
// v13: v11 geometry (best: 102.7us) + deterministic phase-A pipeline.
//   Measured arithmetic (v3 counters): phase A = ~2900 VALU inst/thread (17/dword blend
//   + ~70/tap 64-bit addressing) at only 22% busy -> exposed L2 latency in the per-tap
//   load->blend chain is the cost, and hipcc won't pipeline taps on its own.
//   Phase A rewrite (phase B untouched, verified):
//   - dy/dx: 18 asm global_load_dword (uniform SGPR base + 32b voffset), one drain.
//     ALL phase-A VMEM is inline asm -> no compiler waitcnt-accounting hazards.
//   - all 36 corner voffsets (yc<<14 | xc<<8 | cb2) + 36 bilinear weights computed
//     up front (saves most of the 64-bit addressing VALU).
//   - gathers in 3 groups of 3 taps: 24 back-to-back asm global_load_dwordx4
//     (base+voff, offset:0/16), s_waitcnt vmcnt(0) + sched_barrier(0) (rule #18),
//     then blend group -> stash. 24 loads pipeline in L1/L2; 3 drains total.
//   - keeps: reg stash (no S buffer), XCD-local n=bid&7, cvt_pk_bf16, padded SROW,
//     verified wt2 fragment layout, launch_bounds(512,2) (1 block/CU, 256-VGPR budget).
// ws: xt 8MB @0; wt2 288KB @8388608. Fully rewritten each launch.

#define H  64
#define W  64
#define CIN 128
#define COUT 128
#define NB 8
#define KK 9
#define SROW (CIN + 8)

typedef short bf16x8 __attribute__((ext_vector_type(8)));
typedef float f32x4  __attribute__((ext_vector_type(4)));

// unsinkable loads: uniform SGPR base + 32-bit VGPR byte-offset (+13b imm)
#define GLD4(dst, voff, base, IMM) \
    asm volatile("global_load_dwordx4 %0, %1, %2 offset:" IMM \
                 : "=v"(dst) : "v"(voff), "s"(base))
#define GLD1(dst, voff, base) \
    asm volatile("global_load_dword %0, %1, %2" \
                 : "=v"(dst) : "v"(voff), "s"(base))
#define DRAIN() { asm volatile("s_waitcnt vmcnt(0)" ::: "memory"); \
                  __builtin_amdgcn_sched_barrier(0); }

__device__ __forceinline__ unsigned short f2bf(float f) {
    unsigned u = __builtin_bit_cast(unsigned, f);
    u += 0x7FFFu + ((u >> 16) & 1u);          // round-nearest-even
    return (unsigned short)(u >> 16);
}
__device__ __forceinline__ unsigned cvt_pk_bf16(float lo, float hi) {
    unsigned r;
    asm("v_cvt_pk_bf16_f32 %0, %1, %2" : "=v"(r) : "v"(lo), "v"(hi));
    return r;                                  // low16 = bf16(lo), high16 = bf16(hi), RNE
}
__device__ __forceinline__ float lo_f(unsigned u) { return __builtin_bit_cast(float, u << 16); }
__device__ __forceinline__ float hi_f(unsigned u) { return __builtin_bit_cast(float, u & 0xFFFF0000u); }

// Merged prep: blocks [0, NB*H) transpose x (NCHW fp32 -> NHWC bf16), XCD-local (n = b&7);
// blocks [NB*H, NB*H+576): weight fp32 [co][c][kk] -> wt2 fragment-contiguous bf16:
//   wt2 flat idx = ((((kk*4 + c4)*2 + nt)*4 + ct)*64 + lm*4 + lq)*8 + e
//   where co = c4*32 + nt*16 + lm, ch = ct*32 + lq*8 + e.   [verified rounds 6-11]
__global__ void prep_all(const float* __restrict__ x, const float* __restrict__ w,
                         unsigned short* __restrict__ xt, unsigned short* __restrict__ wt) {
    int b = blockIdx.x;
    int t = threadIdx.x;
    if (b >= NB * H) {                        // ---- weight part ----
        int idx = (b - NB * H) * 256 + t;
        if (idx < KK * COUT * CIN) {
            int e  = idx & 7;
            int lq = (idx >> 3) & 3;
            int lm = (idx >> 5) & 15;
            int ct = (idx >> 9) & 3;
            int nt = (idx >> 11) & 1;
            int c4 = (idx >> 12) & 3;
            int kk = idx >> 14;
            int co = (c4 << 5) + (nt << 4) + lm;
            int ch = (ct << 5) + (lq << 3) + e;
            wt[idx] = f2bf(w[(co * CIN + ch) * KK + kk]);
        }
        return;
    }
    // ---- x-transpose part: one (n,y) row per block; n = b&7 matches XCD map ----
    __shared__ float tile[CIN][W + 4];
    int n = b & 7, y = b >> 3;
    const float* src = x + ((size_t)n * CIN * H + y) * W;
    #pragma unroll
    for (int it = 0; it < 8; ++it) {
        int idx = it * 256 + t;               // 0..2047 float4s
        int c  = idx >> 4;
        int x4 = (idx & 15) << 2;
        int xs = (x4 + ((c >> 5) << 4)) & 63; // rotate-swizzle per 32-ch group
        *(float4*)&tile[c][xs] = *(const float4*)(src + (size_t)c * H * W + x4);
    }
    __syncthreads();
    int xp = t >> 2;                          // x position 0..63
    int cbch = (t & 3) << 5;                  // channel base (32-ch chunk)
    int xr = (xp + ((cbch >> 5) << 4)) & 63;
    unsigned short* dst = xt + (((size_t)(n * H + y) * W + xp) * CIN + cbch);
    unsigned rr[16];
    #pragma unroll
    for (int i = 0; i < 16; ++i)
        rr[i] = cvt_pk_bf16(tile[cbch + 2 * i][xr], tile[cbch + 2 * i + 1][xr]);
    #pragma unroll
    for (int i = 0; i < 4; ++i)
        ((uint4*)dst)[i] = make_uint4(rr[4*i], rr[4*i+1], rr[4*i+2], rr[4*i+3]);
}

// Fused kernel: one block per (n, ho); n = bid&7 (XCD-local). 512 threads = 8 waves.
__global__ __launch_bounds__(512, 2) void fused_main(
        const float* __restrict__ offs, const unsigned short* __restrict__ xt,
        const unsigned short* __restrict__ wt, float* __restrict__ out) {
    __shared__ __attribute__((aligned(16))) unsigned short samp[2][64][SROW];  // 34,816 B

    int b = blockIdx.x;
    int n = b & 7, ho = b >> 3;
    int t = threadIdx.x;
    int lane = t & 63, wv = t >> 6;
    int lm = lane & 15, lq = lane >> 4;

    // shared thread map for both phases: pos = t>>3 (0..63), 16-ch chunk = t&7
    int pos = t >> 3;
    int cb  = (t & 7) << 4;                   // channel units
    int cb2 = cb << 1;                        // bytes

    // -------- phase A: sample 9 taps -> stash, asm-pipelined (no barriers) --------
    const float* offs_b = offs + (size_t)(n * 2 * KK) * H * W + (size_t)ho * W;  // uniform
    const unsigned short* xt_b = xt + (size_t)n * H * W * CIN;                   // uniform

    // 1) all 18 offset loads (asm), one drain
    float dyv[KK], dxv[KK];
    #pragma unroll
    for (int tap = 0; tap < KK; ++tap) {
        GLD1(dyv[tap], (unsigned)(((2 * tap) * H * W + pos) * 4), offs_b);
        GLD1(dxv[tap], (unsigned)(((2 * tap + 1) * H * W + pos) * 4), offs_b);
    }
    DRAIN();

    // 2) all 36 voffsets + 36 bilinear weights up front (pure VALU)
    unsigned vo[KK][4];
    float bw[KK][4];
    #pragma unroll
    for (int tap = 0; tap < KK; ++tap) {
        float py = (float)(ho - 1 + tap / 3) + dyv[tap];
        float px = (float)(pos - 1 + tap % 3) + dxv[tap];
        float y0f = floorf(py), x0f = floorf(px);
        float wy1 = py - y0f, wx1 = px - x0f;
        float wy0 = 1.f - wy1, wx0 = 1.f - wx1;
        int y0 = (int)y0f, x0 = (int)x0f;
        int y1 = y0 + 1, x1 = x0 + 1;
        bool vy0 = (unsigned)y0 < (unsigned)H, vy1 = (unsigned)y1 < (unsigned)H;
        bool vx0 = (unsigned)x0 < (unsigned)W, vx1 = (unsigned)x1 < (unsigned)W;
        bw[tap][0] = (vy0 && vx0) ? wy0 * wx0 : 0.f;
        bw[tap][1] = (vy0 && vx1) ? wy0 * wx1 : 0.f;
        bw[tap][2] = (vy1 && vx0) ? wy1 * wx0 : 0.f;
        bw[tap][3] = (vy1 && vx1) ? wy1 * wx1 : 0.f;
        int yc0 = min(max(y0, 0), H - 1), yc1 = min(max(y1, 0), H - 1);
        int xc0 = min(max(x0, 0), W - 1), xc1 = min(max(x1, 0), W - 1);
        vo[tap][0] = (unsigned)((yc0 << 14) + (xc0 << 8) + cb2);
        vo[tap][1] = (unsigned)((yc0 << 14) + (xc1 << 8) + cb2);
        vo[tap][2] = (unsigned)((yc1 << 14) + (xc0 << 8) + cb2);
        vo[tap][3] = (unsigned)((yc1 << 14) + (xc1 << 8) + cb2);
    }

    // 3) gathers in 3 groups of 3 taps: issue 24 -> drain -> blend
    unsigned stash[KK][8];                    // 72 VGPR, statically indexed
    #pragma unroll
    for (int grp = 0; grp < 3; ++grp) {
        uint4 gq[3][8];                       // 96 VGPR in flight
        #pragma unroll
        for (int i = 0; i < 3; ++i) {
            int tap = grp * 3 + i;
            GLD4(gq[i][0], vo[tap][0], xt_b, "0");
            GLD4(gq[i][1], vo[tap][0], xt_b, "16");
            GLD4(gq[i][2], vo[tap][1], xt_b, "0");
            GLD4(gq[i][3], vo[tap][1], xt_b, "16");
            GLD4(gq[i][4], vo[tap][2], xt_b, "0");
            GLD4(gq[i][5], vo[tap][2], xt_b, "16");
            GLD4(gq[i][6], vo[tap][3], xt_b, "0");
            GLD4(gq[i][7], vo[tap][3], xt_b, "16");
        }
        DRAIN();
        #pragma unroll
        for (int i = 0; i < 3; ++i) {
            int tap = grp * 3 + i;
            float w00 = bw[tap][0], w01 = bw[tap][1], w10 = bw[tap][2], w11 = bw[tap][3];
            #pragma unroll
            for (int h = 0; h < 2; ++h) {     // h: 16B chunk (channels 8h..8h+7)
                const unsigned* a0 = (const unsigned*)&gq[i][0 + h];
                const unsigned* a1 = (const unsigned*)&gq[i][2 + h];
                const unsigned* a2 = (const unsigned*)&gq[i][4 + h];
                const unsigned* a3 = (const unsigned*)&gq[i][6 + h];
                #pragma unroll
                for (int q = 0; q < 4; ++q) {
                    float v0 = w00*lo_f(a0[q]) + w01*lo_f(a1[q]) + w10*lo_f(a2[q]) + w11*lo_f(a3[q]);
                    float v1 = w00*hi_f(a0[q]) + w01*hi_f(a1[q]) + w10*hi_f(a2[q]) + w11*hi_f(a3[q]);
                    stash[tap][4*h + q] = cvt_pk_bf16(v0, v1);
                }
            }
        }
    }

    // -------- phase B: GEMM over taps (8 waves, wave = 64 pos x 16 co) [verified] ----
    f32x4 acc[4];
    #pragma unroll
    for (int mt = 0; mt < 4; ++mt) acc[mt] = f32x4{0.f, 0.f, 0.f, 0.f};

    int slot = (lm << 2) + lq;
    // wave wv covers co block wv*16: wt2 base (tap*8 + wv)*2048 + slot*8; frag ct at +ct*512
    const unsigned short* wvbase = wt + ((size_t)wv << 11) + (slot << 3);

    // prologue: stage tap 0 from regs
    {
        unsigned short* ld = &samp[0][pos][cb];
        *(uint4*)(ld)     = make_uint4(stash[0][0], stash[0][1], stash[0][2], stash[0][3]);
        *(uint4*)(ld + 8) = make_uint4(stash[0][4], stash[0][5], stash[0][6], stash[0][7]);
    }
    __syncthreads();

    #pragma unroll
    for (int tap = 0; tap < KK; ++tap) {
        if (tap < KK - 1) {                   // stage tap+1 into the other buffer
            unsigned short* ld = &samp[(tap + 1) & 1][pos][cb];
            *(uint4*)(ld)     = make_uint4(stash[tap+1][0], stash[tap+1][1],
                                           stash[tap+1][2], stash[tap+1][3]);
            *(uint4*)(ld + 8) = make_uint4(stash[tap+1][4], stash[tap+1][5],
                                           stash[tap+1][6], stash[tap+1][7]);
        }
        // B-frags for this tap (verified wt2 layout), 4 x b128 per wave-lane
        const unsigned short* wkb = wvbase + ((size_t)(tap << 3) << 11);
        bf16x8 bW[4];
        #pragma unroll
        for (int ct = 0; ct < 4; ++ct)
            bW[ct] = *(const bf16x8*)(wkb + (ct << 9));

        __builtin_amdgcn_s_setprio(1);
        #pragma unroll
        for (int ct = 0; ct < 4; ++ct) {
            bf16x8 a[4];
            #pragma unroll
            for (int mt = 0; mt < 4; ++mt)
                a[mt] = *(const bf16x8*)&samp[tap & 1][lm + (mt << 4)][(ct << 5) + (lq << 3)];
            #pragma unroll
            for (int mt = 0; mt < 4; ++mt)
                acc[mt] = __builtin_amdgcn_mfma_f32_16x16x32_bf16(a[mt], bW[ct], acc[mt], 0, 0, 0);
        }
        __builtin_amdgcn_s_setprio(0);
        __syncthreads();
    }

    // epilogue: D[m = mt*16 + lq*4 + j][col = lm] -> out[n][co][ho][wo], float4 over wo
    int co = (wv << 4) + lm;
    #pragma unroll
    for (int mt = 0; mt < 4; ++mt) {
        int wob = (mt << 4) + (lq << 2);
        *(f32x4*)(out + (((size_t)(n * COUT + co) * H + ho) * W + wob)) = acc[mt];
    }
}

extern "C" void kernel_launch(void* const* d_in, const int* in_sizes, int n_in,
                              void* d_out, int out_size, void* d_ws, size_t ws_size,
                              hipStream_t stream) {
    const float* x      = (const float*)d_in[0];   // (8,128,64,64)
    const float* offset = (const float*)d_in[1];   // (8,18,64,64)
    const float* weight = (const float*)d_in[2];   // (128,128,3,3)
    float* out = (float*)d_out;

    unsigned short* xt = (unsigned short*)d_ws;                                  // 8 MB
    unsigned short* wt = (unsigned short*)((char*)d_ws + 8388608);               // 288 KB

    int wblocks = (KK * COUT * CIN + 255) / 256;   // 576
    hipLaunchKernelGGL(prep_all, dim3(NB * H + wblocks), dim3(256), 0, stream,
                       x, weight, xt, wt);
    hipLaunchKernelGGL(fused_main, dim3(NB * H), dim3(512), 0, stream,
                       offset, xt, wt, out);
}